// Round 3
// baseline (55906.018 us; speedup 1.0000x reference)
//
#include <hip/hip_runtime.h>
#include <hip/hip_bf16.h>
#include <cstdint>

// Problem constants
#define V_ 100000
#define E_ 300
#define H_ 768
#define T_ 20
#define S_ 8192
#define SENT 0xFFC0DEADu  // NaN bit pattern; real h is never NaN

// d_ws layout: float hb[(S_+1)][2][H_]  (slot t = h after t steps; slot 0 zeros,
// slots 1..S poisoned to SENT), then u32 flag (1 = inputs are fp32), u32 diag.

__device__ __forceinline__ float ldf(const void* p, int f32, size_t i) {
    return f32 ? ((const float*)p)[i]
               : __bfloat162float(((const __hip_bfloat16*)p)[i]);
}

// ---- fast activations: raw v_exp_f32 / v_rcp_f32 (err ~1e-7, contractive in c) ----
#if __has_builtin(__builtin_amdgcn_exp2f)
#define EXP2F(x) __builtin_amdgcn_exp2f(x)
#else
#define EXP2F(x) exp2f(x)
#endif
#if __has_builtin(__builtin_amdgcn_rcpf)
#define RCPF(x) __builtin_amdgcn_rcpf(x)
#else
#define RCPF(x) (1.0f / (x))
#endif
#define LOG2E_ 1.4426950408889634f

__device__ __forceinline__ float sigf(float x) {
    return RCPF(1.0f + EXP2F(-LOG2E_ * x));
}
__device__ __forceinline__ float tanhf_fast(float x) {
    // tanh(x) = 1 - 2/(exp2(2*log2e*x) + 1); exact at 0, correct at +-inf
    return 1.0f - 2.0f * RCPF(1.0f + EXP2F((2.0f * LOG2E_) * x));
}

// ---- DPP wave-reduce: sum of all 64 lanes lands in lane 63 (~6 VALU-latency ops) ----
#if __has_builtin(__builtin_amdgcn_update_dpp)
#define DPP_ADD_(x, ctrl, rmask)                                                   \
    (x) += __int_as_float(__builtin_amdgcn_update_dpp(                             \
        0, __float_as_int(x), (ctrl), (rmask), 0xf, false))
__device__ __forceinline__ float reduce63(float x) {
    DPP_ADD_(x, 0x111, 0xf);  // row_shr:1
    DPP_ADD_(x, 0x112, 0xf);  // row_shr:2
    DPP_ADD_(x, 0x114, 0xf);  // row_shr:4
    DPP_ADD_(x, 0x118, 0xf);  // row_shr:8  -> lane15 of each row = row sum
    DPP_ADD_(x, 0x142, 0xa);  // row_bcast:15 -> rows 1,3 add rows 0,2
    DPP_ADD_(x, 0x143, 0xc);  // row_bcast:31 -> rows 2,3 add rows 0+1
    return x;                 // lane 63 holds the full 64-lane sum
}
#else
__device__ __forceinline__ float reduce63(float x) {
    #pragma unroll
    for (int m = 1; m < 64; m <<= 1) x += __shfl_xor(x, m, 64);
    return x;
}
#endif

__global__ void init_h_kernel(uint32_t* __restrict__ hb_u, int n,
                              const uint16_t* __restrict__ probe) {
    if (blockIdx.x == 0) {
        // Runtime dtype detection on b_ih_f (uniform +-0.036): bf16 buffer has no
        // element with exponent >= 0x81; fp32 buffer read as u16 halves: ~50% hits.
        __shared__ int tot;
        if (threadIdx.x == 0) tot = 0;
        __syncthreads();
        int cnt = 0;
        for (int i = threadIdx.x; i < 2048; i += blockDim.x) {
            uint32_t e = (probe[i] >> 7) & 0xFF;
            cnt += (e >= 0x81) ? 1 : 0;
        }
        atomicAdd(&tot, cnt);
        __syncthreads();
        if (threadIdx.x == 0) {
            hb_u[n]     = (tot >= 32) ? 1u : 0u;  // 1 = fp32 inputs
            hb_u[n + 1] = 0u;                     // diag: sync-failure flag
        }
    }
    int stride = gridDim.x * blockDim.x;
    for (int i = blockIdx.x * blockDim.x + threadIdx.x; i < n; i += stride)
        hb_u[i] = (i < 2 * H_) ? 0u : SENT;
}

// Vectorized MALL-coherent poll read: 48 B at p (16B-aligned), bypassing L1/L2.
// NOTE: the vmcnt(0) also drains this wave's in-flight emb prefetch + publish
// atomics — that wait overlaps the spin for producers (who are ~1 RTT behind),
// so it costs ~nothing on the critical chain.
__device__ __forceinline__ void poll48(const uint32_t* p, uint4& a, uint4& b, uint4& c) {
    asm volatile(
        "global_load_dwordx4 %0, %3, off sc0 sc1\n\t"
        "global_load_dwordx4 %1, %3, off offset:16 sc0 sc1\n\t"
        "global_load_dwordx4 %2, %3, off offset:32 sc0 sc1\n\t"
        "s_waitcnt vmcnt(0)"
        : "=&v"(a), "=&v"(b), "=&v"(c)
        : "v"(p)
        : "memory");
}

// Producer-side h publish: no-return global_atomic_swap executes AT the MALL
// (the agent coherence point) — visible to sc0/sc1 pollers when it executes.
__device__ __forceinline__ void publish_u32(uint32_t* addr, uint32_t val) {
    asm volatile("global_atomic_swap %0, %1, off"
                 :: "v"(addr), "v"(val) : "memory");
}

// 768 blocks x 64 threads = 768 INDEPENDENT waves (384 per direction), each owning
// TWO adjacent h elements (e0, e0+1; 8 gate rows).  There is NO barrier, NO LDS,
// NO intra-block coupling anywhere in the scan: h slots are write-once and
// poison-synced, so each wave polls the full previous-h vector (lane l owns dwords
// [12l,12l+12)) straight into its own VGPRs, computes, and publishes its 2 dwords.
// This deletes the old poll->LDS->barrier relay (~1.5-2us/step of rendezvous +
// relay + forced vmcnt drains) from the serial chain.  2 elements/wave keeps the
// MALL poll-spin traffic at ~8 TB/s worst case (768 pollers x 3KB/spin).
__launch_bounds__(64, 1)
__global__ void lstm_scan_kernel(const int* __restrict__ idx,
                                 const void* __restrict__ emb,
                                 const void* __restrict__ Wih_f, const void* __restrict__ Whh_f,
                                 const void* __restrict__ bih_f, const void* __restrict__ bhh_f,
                                 const void* __restrict__ Wih_b, const void* __restrict__ Whh_b,
                                 const void* __restrict__ bih_b, const void* __restrict__ bhh_b,
                                 float* __restrict__ hb,
                                 const uint32_t* __restrict__ flagp,
                                 uint32_t* __restrict__ diag)
{
    const int f32  = (int)flagp[0];
    const int lane = threadIdx.x & 63;
    const int blk  = blockIdx.x;
    const int dir  = (blk >= 384) ? 1 : 0;
    const int w    = dir ? (blk - 384) : blk;
    const int e0   = 2 * w;                 // this wave's two h elements: e0, e0+1

    const void* Wih = dir ? Wih_b : Wih_f;
    const void* Whh = dir ? Whh_b : Whh_f;
    const void* bih = dir ? bih_b : bih_f;
    const void* bhh = dir ? bhh_b : bhh_f;

    // Per-lane resident weights (fp32 in VGPRs):
    //   recurrent: 12 h-chunk per lane per gate per element  (2*4*12 = 96 regs)
    //   input:      5 x-chunk per lane per gate per element  (2*4*5  = 40 regs)
    float whh[2][4][12];
    float wih[2][4][5];
    float bias[2][4];
    #pragma unroll
    for (int p = 0; p < 2; ++p) {
        #pragma unroll
        for (int g = 0; g < 4; ++g) {
            int row = g * H_ + e0 + p;  // PyTorch gate order i,f,g,o stacked on 4H
            #pragma unroll
            for (int j = 0; j < 12; ++j)
                whh[p][g][j] = ldf(Whh, f32, (size_t)row * H_ + 12 * lane + j);
            #pragma unroll
            for (int j = 0; j < 5; ++j) {
                int k = 5 * lane + j;
                wih[p][g][j] = (k < E_) ? ldf(Wih, f32, (size_t)row * E_ + k) : 0.0f;
            }
            bias[p][g] = ldf(bih, f32, row) + ldf(bhh, f32, row);
        }
    }

    // x pipeline: xc = x_t, xn = x_{t+1} (in flight a full step ahead)
    float xc[5], xn[5];
    {
        size_t b0 = (size_t)idx[0] * E_;
        size_t b1 = (size_t)idx[1] * E_;
        #pragma unroll
        for (int j = 0; j < 5; ++j) {
            int k = 5 * lane + j;
            xc[j] = (k < E_) ? ldf(emb, f32, b0 + k) : 0.0f;
            xn[j] = (k < E_) ? ldf(emb, f32, b1 + k) : 0.0f;
        }
    }

    const uint32_t* hb_u = (const uint32_t*)hb;
    uint32_t*       hb_w = (uint32_t*)hb;
    float c0 = 0.0f, c1 = 0.0f;
    int fuel = 4000000;  // safety: converts a would-be deadlock into a finite run

    for (int t = 0; t < S_; ++t) {
        // ---- poll h(t) straight into VGPRs: lane owns dwords [12*lane, 12*lane+12)
        size_t hbase = ((size_t)t * 2 + dir) * H_ + 12 * lane;
        const uint32_t* p = hb_u + hbase;
        uint4 a, b, cc;
        for (;;) {
            poll48(p, a, b, cc);
            bool ok = (a.x != SENT) & (a.y != SENT) & (a.z != SENT) & (a.w != SENT) &
                      (b.x != SENT) & (b.y != SENT) & (b.z != SENT) & (b.w != SENT) &
                      (cc.x != SENT) & (cc.y != SENT) & (cc.z != SENT) & (cc.w != SENT);
            if (__all(ok)) break;
            if (--fuel < 0) break;
            __builtin_amdgcn_s_sleep(1);
        }
        uint32_t v[12] = {a.x, a.y, a.z, a.w, b.x, b.y, b.z, b.w, cc.x, cc.y, cc.z, cc.w};
        if (fuel < 0) {  // sync failure: flag it, substitute finite marker
            if (lane == 0) atomicOr(diag, 1u);
            #pragma unroll
            for (int j = 0; j < 12; ++j)
                if (v[j] == SENT) v[j] = __float_as_uint(1000.0f);
        }
        float hloc[12];
        #pragma unroll
        for (int j = 0; j < 12; ++j) hloc[j] = __uint_as_float(v[j]);

        // ---- gates: 2 elements x 4 gates x (12 recurrent + 5 input) FMA
        float acc[2][4];
        #pragma unroll
        for (int p2 = 0; p2 < 2; ++p2) {
            #pragma unroll
            for (int g = 0; g < 4; ++g) {
                float s = 0.0f;
                #pragma unroll
                for (int j = 0; j < 12; ++j) s = fmaf(whh[p2][g][j], hloc[j], s);
                #pragma unroll
                for (int j = 0; j < 5; ++j)  s = fmaf(wih[p2][g][j], xc[j], s);
                acc[p2][g] = s;
            }
        }
        #pragma unroll
        for (int p2 = 0; p2 < 2; ++p2)
            #pragma unroll
            for (int g = 0; g < 4; ++g) acc[p2][g] = reduce63(acc[p2][g]);

        // ---- rotate x pipeline + issue x(t+2) BEFORE the divergent epilogue:
        // the loads get the whole next poll phase (>= 1 producer RTT) to drain.
        #pragma unroll
        for (int j = 0; j < 5; ++j) xc[j] = xn[j];
        if (t + 2 < S_) {
            size_t bnext = (size_t)idx[t + 2] * E_;
            #pragma unroll
            for (int j = 0; j < 5; ++j) {
                int k = 5 * lane + j;
                xn[j] = (k < E_) ? ldf(emb, f32, bnext + k) : 0.0f;
            }
        }

        // ---- epilogue on lane 63 (holds the full sums): activations, c update, publish
        if (lane == 63) {
            float gi0 = sigf(acc[0][0] + bias[0][0]);
            float gf0 = sigf(acc[0][1] + bias[0][1]);
            float gg0 = tanhf_fast(acc[0][2] + bias[0][2]);
            float go0 = sigf(acc[0][3] + bias[0][3]);
            c0 = gf0 * c0 + gi0 * gg0;
            float hv0 = go0 * tanhf_fast(c0);

            float gi1 = sigf(acc[1][0] + bias[1][0]);
            float gf1 = sigf(acc[1][1] + bias[1][1]);
            float gg1 = tanhf_fast(acc[1][2] + bias[1][2]);
            float go1 = sigf(acc[1][3] + bias[1][3]);
            c1 = gf1 * c1 + gi1 * gg1;
            float hv1 = go1 * tanhf_fast(c1);

            size_t o = ((size_t)(t + 1) * 2 + dir) * H_ + e0;
            publish_u32(hb_w + o,     __float_as_uint(hv0));
            publish_u32(hb_w + o + 1, __float_as_uint(hv1));
        }
    }
}

// out[k] = b_tag[k] + sum_j W_tag[k][j] * hcat[j], hcat = hb[S] = [hf(768); hb(768)]
__global__ void tag_kernel(const void* __restrict__ Wtag,
                           const void* __restrict__ btag,
                           const float* __restrict__ hb,
                           void* __restrict__ out,
                           const uint32_t* __restrict__ flagp,
                           const uint32_t* __restrict__ diag)
{
    const int f32 = (int)flagp[0];
    const float pen = (diag[0] != 0) ? 1.0e6f : 0.0f;  // make sync failure unmistakable
    int wave = threadIdx.x >> 6, lane = threadIdx.x & 63;
    const float* hcat = hb + (size_t)S_ * 2 * H_;  // 1536 floats, [hf; hb]
    for (int k = wave; k < T_; k += 10) {
        float s = 0.0f;
        #pragma unroll
        for (int j = 0; j < 24; ++j)
            s = fmaf(ldf(Wtag, f32, (size_t)k * 2 * H_ + 24 * lane + j),
                     hcat[24 * lane + j], s);
        #pragma unroll
        for (int m = 1; m < 64; m <<= 1) s += __shfl_xor(s, m, 64);
        if (lane == 0) {
            float v = s + ldf(btag, f32, k) + pen;
            if (f32) ((float*)out)[k] = v;
            else     ((__hip_bfloat16*)out)[k] = __float2bfloat16(v);
        }
    }
}

extern "C" void kernel_launch(void* const* d_in, const int* in_sizes, int n_in,
                              void* d_out, int out_size, void* d_ws, size_t ws_size,
                              hipStream_t stream)
{
    const int* idx = (const int*)d_in[0];
    const void* emb   = d_in[1];
    const void* Wih_f = d_in[2];
    const void* Whh_f = d_in[3];
    const void* bih_f = d_in[4];
    const void* bhh_f = d_in[5];
    const void* Wih_b = d_in[6];
    const void* Whh_b = d_in[7];
    const void* bih_b = d_in[8];
    const void* bhh_b = d_in[9];
    const void* Wtag  = d_in[10];
    const void* btag  = d_in[11];

    float* hb = (float*)d_ws;          // (S+1)*2*H*4 = 50,337,792 bytes
    int n = (S_ + 1) * 2 * H_;
    uint32_t* flagp = (uint32_t*)d_ws + n;      // [n] = f32 flag, [n+1] = diag
    uint32_t* diag  = flagp + 1;

    init_h_kernel<<<dim3(4096), dim3(256), 0, stream>>>(
        (uint32_t*)hb, n, (const uint16_t*)bih_f);
    lstm_scan_kernel<<<dim3(768), dim3(64), 0, stream>>>(
        idx, emb, Wih_f, Whh_f, bih_f, bhh_f, Wih_b, Whh_b, bih_b, bhh_b,
        hb, flagp, diag);
    tag_kernel<<<dim3(1), dim3(640), 0, stream>>>(
        Wtag, btag, hb, d_out, flagp, diag);
}

// Round 4
// 36582.907 us; speedup vs baseline: 1.5282x; 1.5282x over previous
//
#include <hip/hip_runtime.h>
#include <hip/hip_bf16.h>
#include <cstdint>

// Problem constants
#define V_ 100000
#define E_ 300
#define H_ 768
#define T_ 20
#define S_ 8192
#define NREP 8            // h-broadcast replicas (contention divider)
#define NDEP 8            // ring depth in time steps
#define SENT 0xFFC0DEADu  // NaN bit pattern; real h is never NaN

// d_ws layout (u32 indices):
//   [0, 98304)          float ring[NREP][NDEP][2][H_]   sync ring (393 KB)
//   [98304], [98305]    f32 flag, diag
//   [98432, 98432+1536) float hlast[2][H_]              final h for tag_kernel
#define RING_N   (NREP * NDEP * 2 * H_)   // 98304
#define FLAG_OFF RING_N
#define HLAST_OFF 98432

__device__ __forceinline__ float ldf(const void* p, int f32, size_t i) {
    return f32 ? ((const float*)p)[i]
               : __bfloat162float(((const __hip_bfloat16*)p)[i]);
}

// ---- fast activations: raw v_exp_f32 / v_rcp_f32 (err ~1e-7, contractive in c) ----
#if __has_builtin(__builtin_amdgcn_exp2f)
#define EXP2F(x) __builtin_amdgcn_exp2f(x)
#else
#define EXP2F(x) exp2f(x)
#endif
#if __has_builtin(__builtin_amdgcn_rcpf)
#define RCPF(x) __builtin_amdgcn_rcpf(x)
#else
#define RCPF(x) (1.0f / (x))
#endif
#define LOG2E_ 1.4426950408889634f

__device__ __forceinline__ float sigf(float x) {
    return RCPF(1.0f + EXP2F(-LOG2E_ * x));
}
__device__ __forceinline__ float tanhf_fast(float x) {
    return 1.0f - 2.0f * RCPF(1.0f + EXP2F((2.0f * LOG2E_) * x));
}

// ---- DPP wave-reduce to lane 63 (~6 VALU-latency ops) ----
#if __has_builtin(__builtin_amdgcn_update_dpp)
#define DPP_ADD_(x, ctrl, rmask)                                                   \
    (x) += __int_as_float(__builtin_amdgcn_update_dpp(                             \
        0, __float_as_int(x), (ctrl), (rmask), 0xf, false))
__device__ __forceinline__ float reduce63(float x) {
    DPP_ADD_(x, 0x111, 0xf);  // row_shr:1
    DPP_ADD_(x, 0x112, 0xf);  // row_shr:2
    DPP_ADD_(x, 0x114, 0xf);  // row_shr:4
    DPP_ADD_(x, 0x118, 0xf);  // row_shr:8
    DPP_ADD_(x, 0x142, 0xa);  // row_bcast:15
    DPP_ADD_(x, 0x143, 0xc);  // row_bcast:31
    return x;                 // lane 63 holds the full 64-lane sum
}
#else
__device__ __forceinline__ float reduce63(float x) {
    #pragma unroll
    for (int m = 1; m < 64; m <<= 1) x += __shfl_xor(x, m, 64);
    return x;
}
#endif

// Uniform broadcast of lane 63's value to all lanes (v_readlane -> SGPR)
__device__ __forceinline__ float bcast63(float x) {
    return __int_as_float(__builtin_amdgcn_readlane(__float_as_int(x), 63));
}

__global__ void init_ring_kernel(uint32_t* __restrict__ ws_u,
                                 const uint16_t* __restrict__ probe) {
    if (blockIdx.x == 0) {
        // Runtime dtype detection on b_ih_f (uniform +-0.036): bf16 buffer has no
        // element with exponent >= 0x81; fp32 buffer read as u16 halves: ~50% hits.
        __shared__ int tot;
        if (threadIdx.x == 0) tot = 0;
        __syncthreads();
        int cnt = 0;
        for (int i = threadIdx.x; i < 2048; i += blockDim.x) {
            uint32_t e = (probe[i] >> 7) & 0xFF;
            cnt += (e >= 0x81) ? 1 : 0;
        }
        atomicAdd(&tot, cnt);
        __syncthreads();
        if (threadIdx.x == 0) {
            ws_u[FLAG_OFF]     = (tot >= 32) ? 1u : 0u;  // 1 = fp32 inputs
            ws_u[FLAG_OFF + 1] = 0u;                     // diag
        }
    }
    // ring: slot 0 of every replica/dir = h(0) = zeros; all other slots = SENT
    int stride = gridDim.x * blockDim.x;
    for (int i = blockIdx.x * blockDim.x + threadIdx.x; i < RING_N; i += stride) {
        int slot = (i % (NDEP * 2 * H_)) / (2 * H_);
        ws_u[i] = (slot == 0) ? 0u : SENT;
    }
}

// Vectorized MALL-coherent poll read: 48 B at p (16B-aligned), bypassing L1/L2.
// The vmcnt(0) also drains this wave's own publish/scrub stores and x prefetch —
// that wait overlaps the spin for other producers, so it is off the global chain,
// and it gives us for free the ordering guarantee: a scrub issued at iteration k
// is COMPLETE before iteration k's poll succeeds (hence before any later publish
// to the same address can be issued).
__device__ __forceinline__ void poll48(const uint32_t* p, uint4& a, uint4& b, uint4& c) {
    asm volatile(
        "global_load_dwordx4 %0, %3, off sc0 sc1\n\t"
        "global_load_dwordx4 %1, %3, off offset:16 sc0 sc1\n\t"
        "global_load_dwordx4 %2, %3, off offset:32 sc0 sc1\n\t"
        "s_waitcnt vmcnt(0)"
        : "=&v"(a), "=&v"(b), "=&v"(c)
        : "v"(p)
        : "memory");
}

// no-return global_atomic_swap: executes at the MALL (agent coherence point),
// visible to sc0/sc1 pollers the moment it executes.
__device__ __forceinline__ void publish_u32(uint32_t* addr, uint32_t val) {
    asm volatile("global_atomic_swap %0, %1, off"
                 :: "v"(addr), "v"(val) : "memory");
}

// 768 blocks x 64 threads = 768 independent waves (384/dir), each owning TWO
// adjacent h elements.  No barriers, no LDS.  Sync through a replicated,
// depth-8 ring of h vectors in the MALL:
//   - consumers poll replica (w & 7) only  -> 48 readers/line (vs 768 in R3)
//   - producers publish to all 8 replicas  (one instr, lanes 0..7 active)
//   - slot (t-1)&7 is re-poisoned by each element's owner at iteration t
//     (provably after all reads of h(t-1): polling h(t) successfully implies
//     every wave finished iteration t-1; the scrub is drained by this
//     iteration's own poll vmcnt(0), so it can never reorder past the fresh
//     publish to the same slot 6 iterations later)
__launch_bounds__(64, 1)
__global__ void lstm_scan_kernel(const int* __restrict__ idx,
                                 const void* __restrict__ emb,
                                 const void* __restrict__ Wih_f, const void* __restrict__ Whh_f,
                                 const void* __restrict__ bih_f, const void* __restrict__ bhh_f,
                                 const void* __restrict__ Wih_b, const void* __restrict__ Whh_b,
                                 const void* __restrict__ bih_b, const void* __restrict__ bhh_b,
                                 uint32_t* __restrict__ ws_u)
{
    const uint32_t* flagp = ws_u + FLAG_OFF;
    uint32_t*       diag  = ws_u + FLAG_OFF + 1;
    uint32_t*       ring  = ws_u;
    uint32_t*       hlast = ws_u + HLAST_OFF;

    const int f32  = (int)flagp[0];
    const int lane = threadIdx.x & 63;
    const int blk  = blockIdx.x;
    const int dir  = (blk >= 384) ? 1 : 0;
    const int w    = dir ? (blk - 384) : blk;
    const int e0   = 2 * w;                 // this wave's two h elements
    const int rrep = w & (NREP - 1);        // replica this wave polls

    const void* Wih = dir ? Wih_b : Wih_f;
    const void* Whh = dir ? Whh_b : Whh_f;
    const void* bih = dir ? bih_b : bih_f;
    const void* bhh = dir ? bhh_b : bhh_f;

    // Per-lane resident weights (fp32 in VGPRs): 96 + 40 + 8 floats.
    float whh[2][4][12];
    float wih[2][4][5];
    float bias[2][4];
    #pragma unroll
    for (int p = 0; p < 2; ++p) {
        #pragma unroll
        for (int g = 0; g < 4; ++g) {
            int row = g * H_ + e0 + p;  // PyTorch gate order i,f,g,o stacked on 4H
            #pragma unroll
            for (int j = 0; j < 12; ++j)
                whh[p][g][j] = ldf(Whh, f32, (size_t)row * H_ + 12 * lane + j);
            #pragma unroll
            for (int j = 0; j < 5; ++j) {
                int k = 5 * lane + j;
                wih[p][g][j] = (k < E_) ? ldf(Wih, f32, (size_t)row * E_ + k) : 0.0f;
            }
            bias[p][g] = ldf(bih, f32, row) + ldf(bhh, f32, row);  // wave-uniform
        }
    }

    // x pipeline: xc = x_t, xn = x_{t+1} (in flight a full step ahead)
    float xc[5], xn[5];
    {
        size_t b0 = (size_t)idx[0] * E_;
        size_t b1 = (size_t)idx[1] * E_;
        #pragma unroll
        for (int j = 0; j < 5; ++j) {
            int k = 5 * lane + j;
            xc[j] = (k < E_) ? ldf(emb, f32, b0 + k) : 0.0f;
            xn[j] = (k < E_) ? ldf(emb, f32, b1 + k) : 0.0f;
        }
    }

    float c0 = 0.0f, c1 = 0.0f;   // cell state, redundantly identical in all lanes
    int fuel = 4000000;           // converts a would-be deadlock into a finite run

    for (int t = 0; t < S_; ++t) {
        // ---- poll h(t) from ring[rrep][t&7][dir] straight into VGPRs ----
        const uint32_t* p = ring +
            (((size_t)(rrep * NDEP + (t & (NDEP - 1))) * 2 + dir) * H_) + 12 * lane;
        uint4 a, b, cc;
        for (;;) {
            poll48(p, a, b, cc);
            bool ok = (a.x != SENT) & (a.y != SENT) & (a.z != SENT) & (a.w != SENT) &
                      (b.x != SENT) & (b.y != SENT) & (b.z != SENT) & (b.w != SENT) &
                      (cc.x != SENT) & (cc.y != SENT) & (cc.z != SENT) & (cc.w != SENT);
            if (__all(ok)) break;
            if (--fuel < 0) break;
            __builtin_amdgcn_s_sleep(1);
        }
        uint32_t v[12] = {a.x, a.y, a.z, a.w, b.x, b.y, b.z, b.w, cc.x, cc.y, cc.z, cc.w};
        if (fuel < 0) {  // sync failure: flag it, substitute finite marker
            if (lane == 0) atomicOr(diag, 1u);
            #pragma unroll
            for (int j = 0; j < 12; ++j)
                if (v[j] == SENT) v[j] = __float_as_uint(1000.0f);
        }

        // ---- scrub slot (t-1)&7 (everyone provably finished reading h(t-1)) ----
        if (t >= 1 && lane < NREP) {
            uint32_t* s = ring +
                (((size_t)(lane * NDEP + ((t - 1) & (NDEP - 1))) * 2 + dir) * H_) + e0;
            publish_u32(s,     SENT);
            publish_u32(s + 1, SENT);
        }

        float hloc[12];
        #pragma unroll
        for (int j = 0; j < 12; ++j) hloc[j] = __uint_as_float(v[j]);

        // ---- gates: 2 elements x 4 gates x (12 recurrent + 5 input) FMA ----
        float acc[2][4];
        #pragma unroll
        for (int p2 = 0; p2 < 2; ++p2) {
            #pragma unroll
            for (int g = 0; g < 4; ++g) {
                float s = 0.0f;
                #pragma unroll
                for (int j = 0; j < 12; ++j) s = fmaf(whh[p2][g][j], hloc[j], s);
                #pragma unroll
                for (int j = 0; j < 5; ++j)  s = fmaf(wih[p2][g][j], xc[j], s);
                acc[p2][g] = s;
            }
        }
        #pragma unroll
        for (int p2 = 0; p2 < 2; ++p2)
            #pragma unroll
            for (int g = 0; g < 4; ++g)
                acc[p2][g] = bcast63(reduce63(acc[p2][g]));  // sum -> all lanes

        // ---- rotate x pipeline + issue x(t+2) (drains in next poll's shadow) ----
        #pragma unroll
        for (int j = 0; j < 5; ++j) xc[j] = xn[j];
        if (t + 2 < S_) {
            size_t bnext = (size_t)idx[t + 2] * E_;
            #pragma unroll
            for (int j = 0; j < 5; ++j) {
                int k = 5 * lane + j;
                xn[j] = (k < E_) ? ldf(emb, f32, bnext + k) : 0.0f;
            }
        }

        // ---- epilogue, redundantly on ALL lanes (no divergent serial tail) ----
        float gi0 = sigf(acc[0][0] + bias[0][0]);
        float gf0 = sigf(acc[0][1] + bias[0][1]);
        float gg0 = tanhf_fast(acc[0][2] + bias[0][2]);
        float go0 = sigf(acc[0][3] + bias[0][3]);
        c0 = gf0 * c0 + gi0 * gg0;
        float hv0 = go0 * tanhf_fast(c0);

        float gi1 = sigf(acc[1][0] + bias[1][0]);
        float gf1 = sigf(acc[1][1] + bias[1][1]);
        float gg1 = tanhf_fast(acc[1][2] + bias[1][2]);
        float go1 = sigf(acc[1][3] + bias[1][3]);
        c1 = gf1 * c1 + gi1 * gg1;
        float hv1 = go1 * tanhf_fast(c1);

        if (t + 1 < S_) {
            // publish to all 8 replicas in parallel: lanes 0..7, one replica each
            if (lane < NREP) {
                uint32_t* d = ring +
                    (((size_t)(lane * NDEP + ((t + 1) & (NDEP - 1))) * 2 + dir) * H_) + e0;
                publish_u32(d,     __float_as_uint(hv0));
                publish_u32(d + 1, __float_as_uint(hv1));
            }
        } else {
            if (lane == 0) {
                publish_u32(hlast + dir * H_ + e0,     __float_as_uint(hv0));
                publish_u32(hlast + dir * H_ + e0 + 1, __float_as_uint(hv1));
            }
        }
    }
}

// out[k] = b_tag[k] + sum_j W_tag[k][j] * hcat[j], hcat = hlast = [hf(768); hb(768)]
__global__ void tag_kernel(const void* __restrict__ Wtag,
                           const void* __restrict__ btag,
                           const uint32_t* __restrict__ ws_u,
                           void* __restrict__ out)
{
    const int f32 = (int)ws_u[FLAG_OFF];
    const float pen = (ws_u[FLAG_OFF + 1] != 0) ? 1.0e6f : 0.0f;
    const float* hcat = (const float*)(ws_u + HLAST_OFF);  // 1536 floats [hf; hb]
    int wave = threadIdx.x >> 6, lane = threadIdx.x & 63;
    for (int k = wave; k < T_; k += 10) {
        float s = 0.0f;
        #pragma unroll
        for (int j = 0; j < 24; ++j)
            s = fmaf(ldf(Wtag, f32, (size_t)k * 2 * H_ + 24 * lane + j),
                     hcat[24 * lane + j], s);
        #pragma unroll
        for (int m = 1; m < 64; m <<= 1) s += __shfl_xor(s, m, 64);
        if (lane == 0) {
            float v = s + ldf(btag, f32, k) + pen;
            if (f32) ((float*)out)[k] = v;
            else     ((__hip_bfloat16*)out)[k] = __float2bfloat16(v);
        }
    }
}

extern "C" void kernel_launch(void* const* d_in, const int* in_sizes, int n_in,
                              void* d_out, int out_size, void* d_ws, size_t ws_size,
                              hipStream_t stream)
{
    const int* idx = (const int*)d_in[0];
    const void* emb   = d_in[1];
    const void* Wih_f = d_in[2];
    const void* Whh_f = d_in[3];
    const void* bih_f = d_in[4];
    const void* bhh_f = d_in[5];
    const void* Wih_b = d_in[6];
    const void* Whh_b = d_in[7];
    const void* bih_b = d_in[8];
    const void* bhh_b = d_in[9];
    const void* Wtag  = d_in[10];
    const void* btag  = d_in[11];

    uint32_t* ws_u = (uint32_t*)d_ws;   // needs < 512 KB

    init_ring_kernel<<<dim3(256), dim3(256), 0, stream>>>(
        ws_u, (const uint16_t*)bih_f);
    lstm_scan_kernel<<<dim3(768), dim3(64), 0, stream>>>(
        idx, emb, Wih_f, Whh_f, bih_f, bhh_f, Wih_b, Whh_b, bih_b, bhh_b, ws_u);
    tag_kernel<<<dim3(1), dim3(640), 0, stream>>>(
        Wtag, btag, ws_u, d_out);
}